// Round 1
// baseline (956.688 us; speedup 1.0000x reference)
//
#include <hip/hip_runtime.h>
#include <cstdint>
#include <cstddef>

// ---------------------------------------------------------------------------
// WeightedTemporalSelfAttention on MI355X.
//   out = softmax((xWq (xWk)^T + chan_bias)/sqrt(2048)) @ (xWv) + b_ch + b_t[0] + PE(0)
// Precision: softmax is near-one-hot (scores span ~1e4 softmax units), so q,k
// and QK^T use split-fp16 (hi+lo, 3 MFMA passes -> ~2^-22 input precision).
// v and attn@v use plain fp16 (linear, tolerant).
// ---------------------------------------------------------------------------

using h8    = __attribute__((ext_vector_type(8))) _Float16;
using h4    = __attribute__((ext_vector_type(4))) _Float16;
using f32x4 = __attribute__((ext_vector_type(4))) float;

__device__ __forceinline__ void gll16(const void* g, void* l) {
  // async global->LDS, 16B/lane; LDS dest = wave-uniform base + lane*16
  __builtin_amdgcn_global_load_lds(
      (const __attribute__((address_space(1))) uint32_t*)g,
      (__attribute__((address_space(3))) uint32_t*)l, 16, 0, 0);
}

// ---------------- elementwise split: fp32 -> fp16 hi + fp16 lo --------------
__global__ __launch_bounds__(256) void split_x_kernel(
    const float* __restrict__ X, _Float16* __restrict__ hi,
    _Float16* __restrict__ lo, int n4)
{
  int i = blockIdx.x * 256 + threadIdx.x;
  if (i >= n4) return;
  float4 v = ((const float4*)X)[i];
  float a[4] = {v.x, v.y, v.z, v.w};
  h4 hh, ll;
#pragma unroll
  for (int e = 0; e < 4; ++e) {
    _Float16 h = (_Float16)a[e];
    hh[e] = h;
    ll[e] = (_Float16)(a[e] - (float)h);
  }
  ((h4*)hi)[i] = hh;
  ((h4*)lo)[i] = ll;
}

// ------------- transpose + split: W[k][n] fp32 -> T{hi,lo}[n][k] fp16 -------
__global__ __launch_bounds__(256) void transpose_split_w(
    const float* __restrict__ W, _Float16* __restrict__ Thi,
    _Float16* __restrict__ Tlo, int D, int writeLo)
{
  __shared__ float t[32][33];
  int n0 = blockIdx.x * 32;
  int k0 = blockIdx.y * 32;
  int tx = threadIdx.x & 31;
  int ty = threadIdx.x >> 5;  // 0..7
  for (int j = ty; j < 32; j += 8)
    t[j][tx] = W[(size_t)(k0 + j) * D + n0 + tx];
  __syncthreads();
  for (int j = ty; j < 32; j += 8) {
    float v = t[tx][j];                          // W[k0+tx][n0+j]
    size_t o = (size_t)(n0 + j) * D + k0 + tx;   // T[n][k]
    _Float16 h = (_Float16)v;
    Thi[o] = h;
    if (writeLo) Tlo[o] = (_Float16)(v - (float)h);
  }
}

// ---------------------------- tiled MFMA GEMM ------------------------------
// C[M,N] = A[M,K] * Bt[N,K]^T   (both operands row-major with K contiguous)
// 128x128 tile, BK=32, 256 threads = 4 waves (2x2), wave = 64x64 = 4x4 frags
// SPLIT: acc += Ahi*Bhi + Ahi*Blo + Alo*Bhi (3 MFMA per frag pair)
constexpr int EPI_QK = 0;   // write C as fp16 hi/lo pair (row-major, ldc)
constexpr int EPI_VT = 1;   // write C^T as fp16 (oh1[col*ldt + row])
constexpr int EPI_S  = 2;   // write C fp32 (row-major, ldc)
constexpr int EPI_CTX = 3;  // out = C + c1 + c2 + PE(odd cols +1), fp32

template<int EPI, bool SPLIT>
__global__ __launch_bounds__(256, 2) void gemm_bt(
    const _Float16* __restrict__ A, const _Float16* __restrict__ Al,
    const _Float16* __restrict__ B, const _Float16* __restrict__ Bl,
    int K, int lda, int ldb, int ldc, int ldt,
    float* __restrict__ of32, _Float16* __restrict__ oh1,
    _Float16* __restrict__ oh2,
    const float* __restrict__ c1, const float* __restrict__ c2)
{
  __shared__ __align__(16) _Float16 sA [128 * 32];
  __shared__ __align__(16) _Float16 sB [128 * 32];
  __shared__ __align__(16) _Float16 sAl[SPLIT ? 128 * 32 : 8];
  __shared__ __align__(16) _Float16 sBl[SPLIT ? 128 * 32 : 8];

  const int tid  = threadIdx.x;
  const int lane = tid & 63;
  const int wave = tid >> 6;
  const int wm = wave >> 1, wn = wave & 1;
  const int m0 = blockIdx.y * 128, n0 = blockIdx.x * 128;

  // staging: chunk c = lane + 64*wave + 256*iss ; row = c>>2, kchunk = c&3
  const int ca = lane + 64 * wave;
  const int ra = ca >> 2, ka = (ca & 3) * 8;
  const int cc = ca + 256;
  const int rb = cc >> 2, kb = (cc & 3) * 8;
  const size_t lo0 = (size_t)wave * 1024;   // LDS byte base, issue 0
  const size_t lo1 = lo0 + 4096;            // issue 1

  const _Float16* gA0 = A + (size_t)(m0 + ra) * lda + ka;
  const _Float16* gA1 = A + (size_t)(m0 + rb) * lda + kb;
  const _Float16* gB0 = B + (size_t)(n0 + ra) * ldb + ka;
  const _Float16* gB1 = B + (size_t)(n0 + rb) * ldb + kb;
  const _Float16* gAl0 = Al ? Al + (size_t)(m0 + ra) * lda + ka : nullptr;
  const _Float16* gAl1 = Al ? Al + (size_t)(m0 + rb) * lda + kb : nullptr;
  const _Float16* gBl0 = Bl ? Bl + (size_t)(n0 + ra) * ldb + ka : nullptr;
  const _Float16* gBl1 = Bl ? Bl + (size_t)(n0 + rb) * ldb + kb : nullptr;

  f32x4 acc[4][4];
#pragma unroll
  for (int i = 0; i < 4; ++i)
#pragma unroll
    for (int j = 0; j < 4; ++j) acc[i][j] = (f32x4){0.f, 0.f, 0.f, 0.f};

  const int fr = lane & 15;        // fragment row within 16-tile
  const int fk = (lane >> 4) * 8;  // fragment k offset (8 halves)

  for (int k0 = 0; k0 < K; k0 += 32) {
    gll16(gA0 + k0, (char*)sA + lo0);
    gll16(gA1 + k0, (char*)sA + lo1);
    gll16(gB0 + k0, (char*)sB + lo0);
    gll16(gB1 + k0, (char*)sB + lo1);
    if constexpr (SPLIT) {
      gll16(gAl0 + k0, (char*)sAl + lo0);
      gll16(gAl1 + k0, (char*)sAl + lo1);
      gll16(gBl0 + k0, (char*)sBl + lo0);
      gll16(gBl1 + k0, (char*)sBl + lo1);
    }
    __syncthreads();   // drains vmcnt before barrier (compiler-inserted)

    h8 af[4], bf[4], afl[4], bfl[4];
#pragma unroll
    for (int mi = 0; mi < 4; ++mi)
      af[mi] = *(const h8*)&sA[(wm * 64 + mi * 16 + fr) * 32 + fk];
#pragma unroll
    for (int ni = 0; ni < 4; ++ni)
      bf[ni] = *(const h8*)&sB[(wn * 64 + ni * 16 + fr) * 32 + fk];
    if constexpr (SPLIT) {
#pragma unroll
      for (int mi = 0; mi < 4; ++mi)
        afl[mi] = *(const h8*)&sAl[(wm * 64 + mi * 16 + fr) * 32 + fk];
#pragma unroll
      for (int ni = 0; ni < 4; ++ni)
        bfl[ni] = *(const h8*)&sBl[(wn * 64 + ni * 16 + fr) * 32 + fk];
    }

#pragma unroll
    for (int mi = 0; mi < 4; ++mi)
#pragma unroll
      for (int ni = 0; ni < 4; ++ni) {
        acc[mi][ni] = __builtin_amdgcn_mfma_f32_16x16x32_f16(
            af[mi], bf[ni], acc[mi][ni], 0, 0, 0);
        if constexpr (SPLIT) {
          acc[mi][ni] = __builtin_amdgcn_mfma_f32_16x16x32_f16(
              af[mi], bfl[ni], acc[mi][ni], 0, 0, 0);
          acc[mi][ni] = __builtin_amdgcn_mfma_f32_16x16x32_f16(
              afl[mi], bf[ni], acc[mi][ni], 0, 0, 0);
        }
      }
    __syncthreads();
  }

  // C/D frag: col = lane&15, row = (lane>>4)*4 + reg   [m89/m91 verified]
  const int drow = (lane >> 4) * 4;
  const int dcol = lane & 15;
#pragma unroll
  for (int mi = 0; mi < 4; ++mi) {
#pragma unroll
    for (int ni = 0; ni < 4; ++ni) {
      const int row = m0 + wm * 64 + mi * 16 + drow;
      const int col = n0 + wn * 64 + ni * 16 + dcol;
      f32x4 v = acc[mi][ni];
      if constexpr (EPI == EPI_S) {
#pragma unroll
        for (int r = 0; r < 4; ++r)
          of32[(size_t)(row + r) * ldc + col] = v[r];
      } else if constexpr (EPI == EPI_QK) {
#pragma unroll
        for (int r = 0; r < 4; ++r) {
          float x = v[r];
          _Float16 hh = (_Float16)x;
          size_t o = (size_t)(row + r) * ldc + col;
          oh1[o] = hh;
          oh2[o] = (_Float16)(x - (float)hh);
        }
      } else if constexpr (EPI == EPI_VT) {
        h4 hh;
#pragma unroll
        for (int r = 0; r < 4; ++r) hh[r] = (_Float16)v[r];
        *(h4*)&oh1[(size_t)col * ldt + row] = hh;
      } else {  // EPI_CTX
#pragma unroll
        for (int r = 0; r < 4; ++r) {
          size_t o = (size_t)(row + r) * ldc + col;
          of32[o] = v[r] + c1[o] + c2[o] + ((col & 1) ? 1.0f : 0.0f);
        }
      }
    }
  }
}

// ------------- row softmax with channel bias; in-place fp32 -> fp16 --------
__global__ __launch_bounds__(256) void softmax_bias_kernel(
    float* __restrict__ S, int N)
{
  const float scale = 0.022097086912079608f;  // 1/sqrt(2048)
  const int row = blockIdx.x;
  float* rp = S + (size_t)row * N;
  const int cblk = row & ~63;  // channel block start (CW=64)
  const int tid = threadIdx.x;

  float vals[16];
  float mx = -3.0e38f;
#pragma unroll
  for (int it = 0; it < 4; ++it) {
    int base = (it * 256 + tid) * 4;
    float4 v = *(const float4*)(rp + base);
    float a[4] = {v.x, v.y, v.z, v.w};
#pragma unroll
    for (int e = 0; e < 4; ++e) {
      int col = base + e;
      float s = a[e];
      if ((col & ~63) == cblk) s += 1.0f;  // bias BEFORE scaling (reference)
      s *= scale;
      vals[it * 4 + e] = s;
      mx = fmaxf(mx, s);
    }
  }
  __shared__ float red[8];
#pragma unroll
  for (int m = 32; m; m >>= 1) mx = fmaxf(mx, __shfl_xor(mx, m, 64));
  if ((tid & 63) == 0) red[tid >> 6] = mx;
  __syncthreads();
  mx = fmaxf(fmaxf(red[0], red[1]), fmaxf(red[2], red[3]));

  float sum = 0.f;
#pragma unroll
  for (int i = 0; i < 16; ++i) {
    float e = __expf(vals[i] - mx);
    vals[i] = e;
    sum += e;
  }
#pragma unroll
  for (int m = 32; m; m >>= 1) sum += __shfl_xor(sum, m, 64);
  if ((tid & 63) == 0) red[4 + (tid >> 6)] = sum;
  __syncthreads();  // also guarantees all reads of rp are complete
  sum = red[4] + red[5] + red[6] + red[7];
  float inv = 1.0f / sum;

  _Float16* op = (_Float16*)rp;  // in-place: fp16 attn over first half of row
#pragma unroll
  for (int it = 0; it < 4; ++it) {
    int base = (it * 256 + tid) * 4;
    h4 hh;
#pragma unroll
    for (int e = 0; e < 4; ++e) hh[e] = (_Float16)(vals[it * 4 + e] * inv);
    *(h4*)(op + base) = hh;
  }
}

// ---------------------------------------------------------------------------
extern "C" void kernel_launch(void* const* d_in, const int* in_sizes, int n_in,
                              void* d_out, int out_size, void* d_ws,
                              size_t ws_size, hipStream_t stream)
{
  (void)in_sizes; (void)n_in; (void)out_size; (void)ws_size;
  const float* x   = (const float*)d_in[0];  // [4096,2048]
  const float* Wq  = (const float*)d_in[1];  // [2048,2048]
  const float* Wk  = (const float*)d_in[2];
  const float* Wv  = (const float*)d_in[3];
  const float* bch = (const float*)d_in[4];  // [4096,2048]
  const float* bt0 = (const float*)d_in[5];  // b_t[0] = first slice
  float* out = (float*)d_out;

  char* ws = (char*)d_ws;
  // phase-1 region [0, 64MiB): x/W splits; phase-2: S (67.1MB) aliases it.
  const size_t O_XHI = 0;
  const size_t O_XLO = O_XHI + 16777216;
  const size_t O_WQH = O_XLO + 16777216;   // 33554432
  const size_t O_WQL = O_WQH + 8388608;
  const size_t O_WKH = O_WQL + 8388608;
  const size_t O_WKL = O_WKH + 8388608;    // ends 67108864
  const size_t O_S   = 0;                  // fp32 scores, 67108864 B (alias)
  const size_t O_WVH = 67108864;
  const size_t O_VT  = O_WVH + 8388608;    // 75497472
  const size_t O_QH  = O_VT + 16777216;    // 92274688
  const size_t O_QL  = O_QH + 16777216;
  const size_t O_KH  = O_QL + 16777216;
  const size_t O_KL  = O_KH + 16777216;    // total need: 159383552 B

  _Float16* xhi = (_Float16*)(ws + O_XHI);
  _Float16* xlo = (_Float16*)(ws + O_XLO);
  _Float16* wqh = (_Float16*)(ws + O_WQH);
  _Float16* wql = (_Float16*)(ws + O_WQL);
  _Float16* wkh = (_Float16*)(ws + O_WKH);
  _Float16* wkl = (_Float16*)(ws + O_WKL);
  _Float16* wvh = (_Float16*)(ws + O_WVH);
  _Float16* vT  = (_Float16*)(ws + O_VT);
  _Float16* qh  = (_Float16*)(ws + O_QH);
  _Float16* ql  = (_Float16*)(ws + O_QL);
  _Float16* kh  = (_Float16*)(ws + O_KH);
  _Float16* kl  = (_Float16*)(ws + O_KL);
  float*    S   = (float*)(ws + O_S);

  // 1) split x (8.4M elems, float4-vectorized)
  split_x_kernel<<<2097152 / 256, 256, 0, stream>>>(x, xhi, xlo, 2097152);
  // 2) transpose+split weights (W[k][n] -> T[n][k])
  dim3 tg(64, 64);
  transpose_split_w<<<tg, 256, 0, stream>>>(Wq, wqh, wql, 2048, 1);
  transpose_split_w<<<tg, 256, 0, stream>>>(Wk, wkh, wkl, 2048, 1);
  transpose_split_w<<<tg, 256, 0, stream>>>(Wv, wvh, nullptr, 2048, 0);

  // 3) q = x@Wq, k = x@Wk  (split, write hi/lo fp16)
  dim3 g1(2048 / 128, 4096 / 128);
  gemm_bt<EPI_QK, true><<<g1, 256, 0, stream>>>(
      xhi, xlo, wqh, wql, 2048, 2048, 2048, 2048, 0,
      nullptr, qh, ql, nullptr, nullptr);
  gemm_bt<EPI_QK, true><<<g1, 256, 0, stream>>>(
      xhi, xlo, wkh, wkl, 2048, 2048, 2048, 2048, 0,
      nullptr, kh, kl, nullptr, nullptr);
  // 4) vT = (x@Wv)^T  (plain fp16, transposed write)
  gemm_bt<EPI_VT, false><<<g1, 256, 0, stream>>>(
      xhi, nullptr, wvh, nullptr, 2048, 2048, 2048, 0, 4096,
      nullptr, vT, nullptr, nullptr, nullptr);

  // 5) S = q@k^T (split; k rows are naturally Bt layout)
  dim3 g2(4096 / 128, 4096 / 128);
  gemm_bt<EPI_S, true><<<g2, 256, 0, stream>>>(
      qh, ql, kh, kl, 2048, 2048, 2048, 4096, 0,
      S, nullptr, nullptr, nullptr, nullptr);

  // 6) softmax((S + chan_bias)/sqrt(d)) -> attn fp16, in place
  softmax_bias_kernel<<<4096, 256, 0, stream>>>(S, 4096);

  // 7) out = attn@v + b_channel + b_t[0] + PE(0)  (attn lda = 8192 halves)
  gemm_bt<EPI_CTX, false><<<g1, 256, 0, stream>>>(
      (const _Float16*)S, nullptr, vT, nullptr, 4096, 8192, 4096, 2048, 0,
      out, nullptr, nullptr, bch, bt0);
}